// Round 3
// baseline (1973.382 us; speedup 1.0000x reference)
//
#include <hip/hip_runtime.h>
#include <math.h>

#define NN 2048
#define KK 20
#define EPSF 1e-5f

__device__ __forceinline__ float lrelu(float v){ return v >= 0.f ? v : 0.2f*v; }

// Sorted (descending, ties by ascending id) top-20 insert. Caller guards d > v[19].
__device__ __forceinline__ void topk20_insert(float d, int idc, float (&v)[KK], int (&id)[KK]){
#pragma unroll
  for (int j = KK-1; j >= 1; --j){
    bool cjm1 = d > v[j-1];
    bool cj   = d > v[j];
    float nv = cjm1 ? v[j-1] : (cj ? d   : v[j]);
    int   ni = cjm1 ? id[j-1] : (cj ? idc : id[j]);
    v[j] = nv; id[j] = ni;
  }
  if (d > v[0]) { v[0] = d; id[0] = idc; }
}

// ---------- stage 1 prep: sq norms + y1 = Wa1*x, t1 = (Wb1-Wa1)*x ----------
__global__ void k_prep1(const float* __restrict__ x, const float* __restrict__ W1,
                        float* __restrict__ Y, float* __restrict__ T, float* __restrict__ SQ){
  __shared__ float wa[64][3], wd[64][3];
  int t = threadIdx.x;
  if (t < 64){
#pragma unroll
    for (int c=0;c<3;c++){
      float a = W1[t*6+c], b2 = W1[t*6+3+c];
      wa[t][c] = a; wd[t][c] = b2 - a;
    }
  }
  __syncthreads();
  int gid = blockIdx.x*256 + t;
  int b = gid >> 11, n = gid & (NN-1);
  float px = x[gid*3+0], py = x[gid*3+1], pz = x[gid*3+2];
  SQ[gid] = px*px + py*py + pz*pz;
  float* yb = Y + ((size_t)b*128)*NN + n;
  float* tb = T + ((size_t)b*128)*NN + n;
#pragma unroll 8
  for (int o=0;o<64;o++){
    yb[(size_t)o*NN] = wa[o][0]*px + wa[o][1]*py + wa[o][2]*pz;
    tb[(size_t)o*NN] = wd[o][0]*px + wd[o][1]*py + wd[o][2]*pz;
  }
}

// ---------- KNN on raw xyz (C=3), QB=16 queries x NSP=16 splits ----------
__global__ __launch_bounds__(256,4) void k_knn3(const float* __restrict__ x, const float* __restrict__ SQ,
                                                int* __restrict__ IDX){
  __shared__ __align__(16) unsigned char smem[40960];
  float* cd = (float*)smem;            // [128][4] xyz+sq  (phase 1)
  float* VL = (float*)smem;            // [256][20]        (phase 2)
  int*   IL = (int*)(smem + 20480);
  int t = threadIdx.x;
  int b = blockIdx.x >> 7;
  int n_base = (blockIdx.x & 127) * 16;
  int ql = t & 15, sp = t >> 4;
  int n = n_base + ql;
  int gq = b*NN + n;
  float qx = x[gq*3], qy = x[gq*3+1], qz = x[gq*3+2];
  float qs = SQ[gq];
  float v[KK]; int id[KK];
#pragma unroll
  for (int i=0;i<KK;i++){ v[i] = -INFINITY; id[i] = 0; }
  int mlo = sp * 8;
  for (int tile=0; tile<16; ++tile){
    int m0 = tile * 128;
    __syncthreads();
#pragma unroll
    for (int i=0;i<2;i++){
      int f2 = t + i*256;
      int m = f2 >> 2, ch = f2 & 3;
      int gm = b*NN + m0 + m;
      cd[f2] = (ch < 3) ? x[gm*3 + ch] : SQ[gm];
    }
    __syncthreads();
    for (int j=mlo; j<mlo+8; ++j){
      float4 c4 = *(const float4*)&cd[j*4];
      float d = 2.f*(qx*c4.x + qy*c4.y + qz*c4.z) - qs - c4.w;
      if (d > v[KK-1]) topk20_insert(d, m0 + j, v, id);
    }
  }
  __syncthreads();
#pragma unroll
  for (int k2=0;k2<KK;k2++){
    VL[(ql*16+sp)*KK + k2] = v[k2];
    IL[(ql*16+sp)*KK + k2] = id[k2];
  }
  __syncthreads();
  if (t < 16){
    float hv[16]; int hi_[16]; int hp[16];
#pragma unroll
    for (int s=0;s<16;s++){ hp[s]=0; hv[s]=VL[(t*16+s)*KK]; hi_[s]=IL[(t*16+s)*KK]; }
    int nq = n_base + t;
    for (int r=0;r<KK;r++){
      float bv = hv[0]; int bi = hi_[0]; int bs = 0;
#pragma unroll
      for (int s=1;s<16;s++){
        bool win = (hv[s] > bv) || ((hv[s] == bv) && (hi_[s] < bi));
        bv = win ? hv[s] : bv; bi = win ? hi_[s] : bi; bs = win ? s : bs;
      }
      IDX[((size_t)b*KK + r)*NN + nq] = bi;
#pragma unroll
      for (int s=0;s<16;s++){
        if (s == bs){
          int np = hp[s] + 1; hp[s] = np;
          bool ok = np < KK;
          hv[s]  = ok ? VL[(t*16+s)*KK + np] : -INFINITY;
          hi_[s] = ok ? IL[(t*16+s)*KK + np] : 0x7FFFFFFF;
        }
      }
    }
  }
}

// ---------- transpose 64ch region to XT[b][n][72] rows (feat[64], sq, zeros) ----------
__global__ __launch_bounds__(256) void k_transpose(const float* __restrict__ src, float* __restrict__ XT){
  __shared__ float Tt[64][65];
  int t = threadIdx.x;
  int b = blockIdx.y;
  int n0 = blockIdx.x * 64;
  const float* sb = src + (size_t)b*256*NN;
#pragma unroll
  for (int i=0;i<16;i++){
    int flat = i*256 + t;
    int c = flat >> 6, n = flat & 63;
    Tt[c][n] = sb[(size_t)c*NN + n0 + n];
  }
  __syncthreads();
  float sqv = 0.f;
  if (t < 64){
#pragma unroll
    for (int c=0;c<64;c++){ float vv = Tt[c][t]; sqv += vv*vv; }
  }
  float* orow = XT + ((size_t)b*NN + n0)*72;
#pragma unroll
  for (int i=0;i<16;i++){
    int flat = i*256 + t;
    int n = flat >> 6, c = flat & 63;
    orow[(size_t)n*72 + c] = Tt[c][n];
  }
  if (t < 64){
    orow[(size_t)t*72 + 64] = sqv;
#pragma unroll
    for (int p=65;p<72;p++) orow[(size_t)t*72 + p] = 0.f;
  }
}

// ---------- KNN on 64-channel features from XT rows, QB=16 x NSP=16 ----------
__global__ __launch_bounds__(256,4) void k_knn64(const float* __restrict__ XT, int* __restrict__ IDX){
  __shared__ __align__(16) unsigned char smem[40960];
  float* cd = (float*)smem;                 // [128][68]  (phase 1)
  float* VL = (float*)smem;                 // [256][20]  (phase 2)
  int*   IL = (int*)(smem + 20480);
  int t = threadIdx.x;
  int b = blockIdx.x >> 7;
  int n_base = (blockIdx.x & 127) * 16;
  int ql = t & 15, sp = t >> 4;
  int n = n_base + ql;
  const float* qrow = XT + ((size_t)b*NN + n)*72;
  float q[64];
#pragma unroll
  for (int c=0;c<64;c+=4){
    float4 qv = *(const float4*)(qrow + c);
    q[c]=qv.x; q[c+1]=qv.y; q[c+2]=qv.z; q[c+3]=qv.w;
  }
  float qs = qrow[64];
  float v[KK]; int id[KK];
#pragma unroll
  for (int i=0;i<KK;i++){ v[i]=-INFINITY; id[i]=0; }
  int mlo = sp * 8;
  int mrow = t >> 1, mh = t & 1;
  for (int tile=0; tile<16; ++tile){
    int m0 = tile*128;
    __syncthreads();
    const float* srow = XT + ((size_t)b*NN + m0 + mrow)*72;
    float* drow = cd + mrow*68;
#pragma unroll
    for (int i=0;i<9;i++){
      int k = mh*9 + i;
      if (k < 17){
        float4 vv4 = *(const float4*)(srow + 4*k);
        *(float4*)(drow + 4*k) = vv4;
      }
    }
    __syncthreads();
    for (int j=mlo; j<mlo+8; ++j){
      const float* crow = cd + j*68;
      float d = 0.f;
#pragma unroll
      for (int c=0;c<64;c+=4){
        float4 c4 = *(const float4*)(crow + c);
        d += q[c]*c4.x + q[c+1]*c4.y + q[c+2]*c4.z + q[c+3]*c4.w;
      }
      d = 2.f*d - qs - crow[64];
      if (d > v[KK-1]) topk20_insert(d, m0 + j, v, id);
    }
  }
  __syncthreads();
#pragma unroll
  for (int k2=0;k2<KK;k2++){
    VL[(ql*16+sp)*KK + k2] = v[k2];
    IL[(ql*16+sp)*KK + k2] = id[k2];
  }
  __syncthreads();
  if (t < 16){
    float hv[16]; int hi_[16]; int hp[16];
#pragma unroll
    for (int s=0;s<16;s++){ hp[s]=0; hv[s]=VL[(t*16+s)*KK]; hi_[s]=IL[(t*16+s)*KK]; }
    int nq = n_base + t;
    for (int r=0;r<KK;r++){
      float bv = hv[0]; int bi = hi_[0]; int bs = 0;
#pragma unroll
      for (int s=1;s<16;s++){
        bool win = (hv[s] > bv) || ((hv[s] == bv) && (hi_[s] < bi));
        bv = win ? hv[s] : bv; bi = win ? hi_[s] : bi; bs = win ? s : bs;
      }
      IDX[((size_t)b*KK + r)*NN + nq] = bi;
#pragma unroll
      for (int s=0;s<16;s++){
        if (s == bs){
          int np = hp[s] + 1; hp[s] = np;
          bool ok = np < KK;
          hv[s]  = ok ? VL[(t*16+s)*KK + np] : -INFINITY;
          hi_[s] = ok ? IL[(t*16+s)*KK + np] : 0x7FFFFFFF;
        }
      }
    }
  }
}

// ---------- gather-max + BN + lrelu; idx loaded once per point, reused for 16 channels ----------
__global__ __launch_bounds__(256) void k_edge_apply(const float* __restrict__ Y, const float* __restrict__ T,
                             const int* __restrict__ IDX,
                             const float* __restrict__ g, const float* __restrict__ be,
                             const float* __restrict__ mu, const float* __restrict__ va,
                             float* __restrict__ OUT, int c_off){
  int t = threadIdx.x;
  int nl = t & 127, oh = t >> 7;
  int n = blockIdx.x*128 + nl;
  int b = blockIdx.z;
  int o0 = blockIdx.y*32 + oh*16;
  int idx[KK];
#pragma unroll
  for (int k2=0;k2<KK;k2++) idx[k2] = IDX[((size_t)b*KK + k2)*NN + n];
  for (int oo=0;oo<16;oo++){
    int o = o0 + oo;
    const float* yrow = Y + ((size_t)b*128 + o)*NN;
    float M = -INFINITY;
#pragma unroll
    for (int k2=0;k2<KK;k2++) M = fmaxf(M, yrow[idx[k2]]);
    float s = g[o] * rsqrtf(va[o] + EPSF);
    float val = s*(M + T[((size_t)b*128 + o)*NN + n] - mu[o]) + be[o];
    OUT[((size_t)b*256 + c_off + o)*NN + n] = lrelu(val);
  }
}

// ---------- y = Wa*X, t = (Wb-Wa)*X  (W is (O,128): [Wa | Wb]) ----------
template<int O>
__global__ __launch_bounds__(256) void k_yt_gemm(const float* __restrict__ X, const float* __restrict__ W,
                                                 float* __restrict__ Y, float* __restrict__ T){
  __shared__ __align__(16) float wa[O][64];
  __shared__ __align__(16) float wd[O][64];
  int t = threadIdx.x;
  for (int i=t; i<O*64; i+=256){
    int o = i >> 6, c = i & 63;
    float a = W[o*128 + c];
    wa[o][c] = a;
    wd[o][c] = W[o*128 + 64 + c] - a;
  }
  __syncthreads();
  int half = t >> 7, ln = t & 127;
  int gid = blockIdx.x*128 + ln;
  int b = gid >> 11, n = gid & (NN-1);
  const float* xb = X + (size_t)b*256*NN;
  float q[64];
#pragma unroll
  for (int c=0;c<64;c++) q[c] = xb[(size_t)c*NN + n];
  int o0 = half * (O/2);
  for (int o=o0; o<o0+O/2; ++o){
    float ay=0.f, at=0.f;
#pragma unroll
    for (int c=0;c<64;c+=4){
      float4 a4 = *(const float4*)&wa[o][c];
      float4 d4 = *(const float4*)&wd[o][c];
      ay += a4.x*q[c] + a4.y*q[c+1] + a4.z*q[c+2] + a4.w*q[c+3];
      at += d4.x*q[c] + d4.y*q[c+1] + d4.z*q[c+2] + d4.w*q[c+3];
    }
    Y[((size_t)b*128 + o)*NN + n] = ay;
    T[((size_t)b*128 + o)*NN + n] = at;
  }
}

// ---------- W4 GEMM with on-the-fly partial max over n ----------
__global__ __launch_bounds__(256) void k_w4max(const float* __restrict__ CAT, const float* __restrict__ W4,
                                               float* __restrict__ PART){
  __shared__ __align__(16) float wt[64][68];   // [c][o]
  __shared__ __align__(16) float ct[64][68];   // [c][n]
  int t = threadIdx.x;
  int io = t >> 4, in_ = t & 15;
  int nb = blockIdx.x * 64, ob = blockIdx.y * 64, b = blockIdx.z;
  const float* catb = CAT + (size_t)b*256*NN;
  float acc[4][4];
#pragma unroll
  for (int r=0;r<4;r++)
#pragma unroll
    for (int c=0;c<4;c++) acc[r][c]=0.f;
  for (int c0=0; c0<256; c0+=64){
    __syncthreads();
    for (int i=t; i<4096; i+=256){
      int oo = i >> 6, cc = i & 63;
      wt[cc][oo] = W4[(size_t)(ob+oo)*256 + c0 + cc];
    }
    for (int i=t; i<4096; i+=256){
      int cc = i >> 6, nn2 = i & 63;
      ct[cc][nn2] = catb[(size_t)(c0+cc)*NN + nb + nn2];
    }
    __syncthreads();
#pragma unroll 4
    for (int c=0;c<64;c++){
      float4 wv = *(const float4*)&wt[c][io*4];
      float4 cv = *(const float4*)&ct[c][in_*4];
      acc[0][0] += wv.x*cv.x; acc[0][1] += wv.x*cv.y; acc[0][2] += wv.x*cv.z; acc[0][3] += wv.x*cv.w;
      acc[1][0] += wv.y*cv.x; acc[1][1] += wv.y*cv.y; acc[1][2] += wv.y*cv.z; acc[1][3] += wv.y*cv.w;
      acc[2][0] += wv.z*cv.x; acc[2][1] += wv.z*cv.y; acc[2][2] += wv.z*cv.z; acc[2][3] += wv.z*cv.w;
      acc[3][0] += wv.w*cv.x; acc[3][1] += wv.w*cv.y; acc[3][2] += wv.w*cv.z; acc[3][3] += wv.w*cv.w;
    }
  }
#pragma unroll
  for (int r=0;r<4;r++){
    float m = fmaxf(fmaxf(acc[r][0], acc[r][1]), fmaxf(acc[r][2], acc[r][3]));
    m = fmaxf(m, __shfl_xor(m, 1));
    m = fmaxf(m, __shfl_xor(m, 2));
    m = fmaxf(m, __shfl_xor(m, 4));
    m = fmaxf(m, __shfl_xor(m, 8));
    if (in_ == 0){
      int o = ob + io*4 + r;
      PART[((size_t)b*1024 + o)*32 + blockIdx.x] = m;
    }
  }
}

__global__ void k_reduce4(const float* __restrict__ PART,
                          const float* __restrict__ g, const float* __restrict__ be,
                          const float* __restrict__ mu, const float* __restrict__ va,
                          float* __restrict__ H4){
  int gid = blockIdx.x*256 + threadIdx.x;   // B*1024
  int o = gid & 1023;
  float M = -INFINITY;
#pragma unroll
  for (int i=0;i<32;i++) M = fmaxf(M, PART[(size_t)gid*32 + i]);
  float s = g[o]*rsqrtf(va[o]+EPSF);
  H4[gid] = lrelu(s*(M - mu[o]) + be[o]);
}

__global__ __launch_bounds__(256) void k_mlp(const float* __restrict__ H4,
      const float* __restrict__ l1w, const float* __restrict__ l1b,
      const float* __restrict__ g5, const float* __restrict__ b5,
      const float* __restrict__ m5, const float* __restrict__ v5,
      const float* __restrict__ l2w, const float* __restrict__ l2b,
      const float* __restrict__ g6, const float* __restrict__ b6,
      const float* __restrict__ m6, const float* __restrict__ v6,
      const float* __restrict__ l3w, const float* __restrict__ l3b,
      float* __restrict__ out){
  __shared__ float h[1024];
  __shared__ float h5[512];
  __shared__ float h6[256];
  int b = blockIdx.x, t = threadIdx.x;
  for (int i=t;i<1024;i+=256) h[i] = H4[b*1024+i];
  __syncthreads();
  for (int o=t;o<512;o+=256){
    float acc = l1b[o];
    for (int c=0;c<1024;c+=4){
      float4 w = *(const float4*)&l1w[(size_t)o*1024 + c];
      acc += w.x*h[c] + w.y*h[c+1] + w.z*h[c+2] + w.w*h[c+3];
    }
    float s = g5[o]*rsqrtf(v5[o]+EPSF);
    h5[o] = lrelu(s*(acc - m5[o]) + b5[o]);
  }
  __syncthreads();
  if (t < 256){
    int o = t;
    float acc = l2b[o];
    for (int c=0;c<512;c+=4){
      float4 w = *(const float4*)&l2w[(size_t)o*512 + c];
      acc += w.x*h5[c] + w.y*h5[c+1] + w.z*h5[c+2] + w.w*h5[c+3];
    }
    float s = g6[o]*rsqrtf(v6[o]+EPSF);
    h6[o] = lrelu(s*(acc - m6[o]) + b6[o]);
  }
  __syncthreads();
  if (t < 128){
    int o = t >> 6, l = t & 63;
    float p = 0.f;
#pragma unroll
    for (int j=0;j<4;j++){ int c = j*64 + l; p += l3w[o*256 + c]*h6[c]; }
    p += __shfl_xor(p, 32); p += __shfl_xor(p, 16); p += __shfl_xor(p, 8);
    p += __shfl_xor(p, 4);  p += __shfl_xor(p, 2);  p += __shfl_xor(p, 1);
    if (l == 0) out[b*2 + o] = p + l3b[o];
  }
}

extern "C" void kernel_launch(void* const* d_in, const int* in_sizes, int n_in,
                              void* d_out, int out_size, void* d_ws, size_t ws_size,
                              hipStream_t stream){
  (void)in_sizes; (void)n_in; (void)out_size; (void)ws_size;
  const float* x    = (const float*)d_in[0];
  const float* W1   = (const float*)d_in[1];
  const float* bn1g = (const float*)d_in[2];
  const float* bn1b = (const float*)d_in[3];
  const float* bn1m = (const float*)d_in[4];
  const float* bn1v = (const float*)d_in[5];
  const float* W2   = (const float*)d_in[6];
  const float* bn2g = (const float*)d_in[7];
  const float* bn2b = (const float*)d_in[8];
  const float* bn2m = (const float*)d_in[9];
  const float* bn2v = (const float*)d_in[10];
  const float* W3   = (const float*)d_in[11];
  const float* bn3g = (const float*)d_in[12];
  const float* bn3b = (const float*)d_in[13];
  const float* bn3m = (const float*)d_in[14];
  const float* bn3v = (const float*)d_in[15];
  const float* W4   = (const float*)d_in[16];
  const float* bn4g = (const float*)d_in[17];
  const float* bn4b = (const float*)d_in[18];
  const float* bn4m = (const float*)d_in[19];
  const float* bn4v = (const float*)d_in[20];
  const float* l1w  = (const float*)d_in[21];
  const float* l1b  = (const float*)d_in[22];
  const float* bn5g = (const float*)d_in[23];
  const float* bn5b = (const float*)d_in[24];
  const float* bn5m = (const float*)d_in[25];
  const float* bn5v = (const float*)d_in[26];
  const float* l2w  = (const float*)d_in[27];
  const float* l2b  = (const float*)d_in[28];
  const float* bn6g = (const float*)d_in[29];
  const float* bn6b = (const float*)d_in[30];
  const float* bn6m = (const float*)d_in[31];
  const float* bn6v = (const float*)d_in[32];
  const float* l3w  = (const float*)d_in[33];
  const float* l3b  = (const float*)d_in[34];

  float* CAT  = (float*)d_ws;                          // [8][256][2048]
  float* Yb   = CAT + (size_t)8*256*NN;                // [8][128][2048]
  float* Tb   = Yb  + (size_t)8*128*NN;                // [8][128][2048]
  float* SQ   = Tb  + (size_t)8*128*NN;                // [8][2048]
  int*   IDX  = (int*)(SQ + (size_t)8*NN);             // [8][20][2048]
  float* PART = (float*)(IDX + (size_t)8*KK*NN);       // [8][1024][32]
  float* H4   = PART + (size_t)8*1024*32;              // [8][1024]
  float* XT   = Tb;  // aliased: XT lifetime (transpose -> knn64) is disjoint
                     // from Tb lifetime (prep1/yt_gemm -> edge_apply), stream-ordered.

  // ---- block 1 ----
  k_prep1<<<64,256,0,stream>>>(x, W1, Yb, Tb, SQ);
  k_knn3<<<1024,256,0,stream>>>(x, SQ, IDX);
  k_edge_apply<<<dim3(16,2,8),256,0,stream>>>(Yb, Tb, IDX, bn1g, bn1b, bn1m, bn1v, CAT, 0);
  // ---- block 2 (features = CAT ch 0..63) ----
  k_transpose<<<dim3(32,8),256,0,stream>>>(CAT, XT);
  k_knn64<<<1024,256,0,stream>>>(XT, IDX);
  k_yt_gemm<64><<<128,256,0,stream>>>(CAT, W2, Yb, Tb);
  k_edge_apply<<<dim3(16,2,8),256,0,stream>>>(Yb, Tb, IDX, bn2g, bn2b, bn2m, bn2v, CAT, 64);
  // ---- block 3 (features = CAT ch 64..127) ----
  k_transpose<<<dim3(32,8),256,0,stream>>>(CAT + (size_t)64*NN, XT);
  k_knn64<<<1024,256,0,stream>>>(XT, IDX);
  k_yt_gemm<128><<<128,256,0,stream>>>(CAT + (size_t)64*NN, W3, Yb, Tb);
  k_edge_apply<<<dim3(16,4,8),256,0,stream>>>(Yb, Tb, IDX, bn3g, bn3b, bn3m, bn3v, CAT, 128);
  // ---- W4 + global max pool ----
  k_w4max<<<dim3(32,16,8),256,0,stream>>>(CAT, W4, PART);
  k_reduce4<<<32,256,0,stream>>>(PART, bn4g, bn4b, bn4m, bn4v, H4);
  // ---- MLP head ----
  k_mlp<<<8,256,0,stream>>>(H4, l1w, l1b, bn5g, bn5b, bn5m, bn5v,
                            l2w, l2b, bn6g, bn6b, bn6m, bn6v, l3w, l3b, (float*)d_out);
}

// Round 4
// 1582.074 us; speedup vs baseline: 1.2473x; 1.2473x over previous
//
#include <hip/hip_runtime.h>
#include <math.h>

#define NN 2048
#define KK 20
#define EPSF 1e-5f

__device__ __forceinline__ float lrelu(float v){ return v >= 0.f ? v : 0.2f*v; }

// Sorted (descending, ties by ascending id) top-20 insert. Caller guards d > v[19].
__device__ __forceinline__ void topk20_insert(float d, int idc, float (&v)[KK], int (&id)[KK]){
#pragma unroll
  for (int j = KK-1; j >= 1; --j){
    bool cjm1 = d > v[j-1];
    bool cj   = d > v[j];
    float nv = cjm1 ? v[j-1] : (cj ? d   : v[j]);
    int   ni = cjm1 ? id[j-1] : (cj ? idc : id[j]);
    v[j] = nv; id[j] = ni;
  }
  if (d > v[0]) { v[0] = d; id[0] = idc; }
}

// ---------- stage 1 prep: sq norms + y1 = Wa1*x, t1 = (Wb1-Wa1)*x ----------
__global__ void k_prep1(const float* __restrict__ x, const float* __restrict__ W1,
                        float* __restrict__ Y, float* __restrict__ T, float* __restrict__ SQ){
  __shared__ float wa[64][3], wd[64][3];
  int t = threadIdx.x;
  if (t < 64){
#pragma unroll
    for (int c=0;c<3;c++){
      float a = W1[t*6+c], b2 = W1[t*6+3+c];
      wa[t][c] = a; wd[t][c] = b2 - a;
    }
  }
  __syncthreads();
  int gid = blockIdx.x*256 + t;
  int b = gid >> 11, n = gid & (NN-1);
  float px = x[gid*3+0], py = x[gid*3+1], pz = x[gid*3+2];
  SQ[gid] = px*px + py*py + pz*pz;
  float* yb = Y + ((size_t)b*128)*NN + n;
  float* tb = T + ((size_t)b*128)*NN + n;
#pragma unroll 8
  for (int o=0;o<64;o++){
    yb[(size_t)o*NN] = wa[o][0]*px + wa[o][1]*py + wa[o][2]*pz;
    tb[(size_t)o*NN] = wd[o][0]*px + wd[o][1]*py + wd[o][2]*pz;
  }
}

// row permute for knn3 LDS tile: rows 8 apart land in distinct bank-quads
__device__ __forceinline__ int PR(int m){ return (m & ~7) | ((m & 7) ^ ((m >> 3) & 3)); }

// ---------- KNN on raw xyz (C=3), QB=16 queries x NSP=16 splits ----------
__global__ __launch_bounds__(256,4) void k_knn3(const float* __restrict__ x, const float* __restrict__ SQ,
                                                int* __restrict__ IDX){
  __shared__ __align__(16) unsigned char smem[40960];
  float* cd = (float*)smem;            // [128][4] xyz+sq, row-permuted  (phase 1)
  float* VL = (float*)smem;            // [256][20]                      (phase 2)
  int*   IL = (int*)(smem + 20480);
  int t = threadIdx.x;
  int b = blockIdx.x >> 7;
  int n_base = (blockIdx.x & 127) * 16;
  int ql = t & 15, sp = t >> 4;
  int n = n_base + ql;
  int gq = b*NN + n;
  float qx = x[gq*3], qy = x[gq*3+1], qz = x[gq*3+2];
  float qs = SQ[gq];
  float v[KK]; int id[KK];
#pragma unroll
  for (int i=0;i<KK;i++){ v[i] = -INFINITY; id[i] = 0; }
  int mlo = sp * 8;
  for (int tile=0; tile<16; ++tile){
    int m0 = tile * 128;
    __syncthreads();
#pragma unroll
    for (int i=0;i<2;i++){
      int f2 = t + i*256;
      int m = f2 >> 2, ch = f2 & 3;
      int gm = b*NN + m0 + m;
      cd[PR(m)*4 + ch] = (ch < 3) ? x[gm*3 + ch] : SQ[gm];
    }
    __syncthreads();
    for (int j=mlo; j<mlo+8; ++j){
      float4 c4 = *(const float4*)&cd[PR(j)*4];
      float d = 2.f*(qx*c4.x + qy*c4.y + qz*c4.z) - qs - c4.w;
      if (d > v[KK-1]) topk20_insert(d, m0 + j, v, id);
    }
  }
  __syncthreads();
#pragma unroll
  for (int k2=0;k2<KK;k2++){
    VL[(ql*16+sp)*KK + k2] = v[k2];
    IL[(ql*16+sp)*KK + k2] = id[k2];
  }
  __syncthreads();
  if (t < 16){
    float hv[16]; int hi_[16]; int hp[16];
#pragma unroll
    for (int s=0;s<16;s++){ hp[s]=0; hv[s]=VL[(t*16+s)*KK]; hi_[s]=IL[(t*16+s)*KK]; }
    int nq = n_base + t;
    for (int r=0;r<KK;r++){
      float bv = hv[0]; int bi = hi_[0]; int bs = 0;
#pragma unroll
      for (int s=1;s<16;s++){
        bool win = (hv[s] > bv) || ((hv[s] == bv) && (hi_[s] < bi));
        bv = win ? hv[s] : bv; bi = win ? hi_[s] : bi; bs = win ? s : bs;
      }
      IDX[((size_t)b*KK + r)*NN + nq] = bi;
#pragma unroll
      for (int s=0;s<16;s++){
        if (s == bs){
          int np = hp[s] + 1; hp[s] = np;
          bool ok = np < KK;
          hv[s]  = ok ? VL[(t*16+s)*KK + np] : -INFINITY;
          hi_[s] = ok ? IL[(t*16+s)*KK + np] : 0x7FFFFFFF;
        }
      }
    }
  }
}

// ---------- squared norms of a 64-channel feature region ----------
__global__ void k_sqnorm(const float* __restrict__ X, float* __restrict__ SQ){
  int gid = blockIdx.x*256 + threadIdx.x;
  int b = gid >> 11, n = gid & (NN-1);
  const float* xb = X + (size_t)b*256*NN;
  float s = 0.f;
#pragma unroll
  for (int c=0;c<64;c++){ float vv = xb[(size_t)c*NN + n]; s += vv*vv; }
  SQ[gid] = s;
}

// ---------- KNN on 64-channel features (col-major strided reads from CAT region) ----------
// LDS tile [128][68] with chunk-XOR swizzle: chunk c>>2 of row m stored at
// position (c>>2) ^ ((m>>3)&3). Writes: 8-way -> 2-way conflict (free);
// phase-2 b128 reads (4 sp-groups, rows 8 apart): 4-way -> conflict-free.
__global__ __launch_bounds__(256) void k_knn64(const float* __restrict__ X, const float* __restrict__ SQ,
                                               int* __restrict__ IDX){
  __shared__ __align__(16) unsigned char smem[40960];
  float* cd = (float*)smem;                 // [128][68]  (phase 1)
  float* cs = (float*)(smem + 34816);       // [128]
  float* VL = (float*)smem;                 // [256][20]  (phase 2)
  int*   IL = (int*)(smem + 20480);
  int t = threadIdx.x;
  int b = blockIdx.x >> 7;
  int n_base = (blockIdx.x & 127) * 16;
  int ql = t & 15, sp = t >> 4;
  int n = n_base + ql;
  const float* xb = X + (size_t)b*256*NN;
  float q[64];
#pragma unroll
  for (int c=0;c<64;c++) q[c] = xb[(size_t)c*NN + n];
  float qs = SQ[b*NN + n];
  float v[KK]; int id[KK];
#pragma unroll
  for (int i=0;i<KK;i++){ v[i]=-INFINITY; id[i]=0; }
  int mlo = sp * 8;
  for (int tile=0; tile<16; ++tile){
    int m0 = tile*128;
    __syncthreads();
#pragma unroll
    for (int i=0;i<32;i++){
      int flat = i*256 + t;
      int c = flat >> 7, m = flat & 127;
      int pos = (((c >> 2) ^ ((m >> 3) & 3)) << 2) | (c & 3);
      cd[m*68 + pos] = xb[(size_t)c*NN + m0 + m];
    }
    if (t < 128) cs[t] = SQ[b*NN + m0 + t];
    __syncthreads();
    for (int j=mlo; j<mlo+8; ++j){
      const float* crow = cd + j*68;
      int swz = (j >> 3) & 3;
      float d = 0.f;
#pragma unroll
      for (int k=0;k<16;k++){
        float4 c4 = *(const float4*)&crow[(k ^ swz) << 2];
        d += q[4*k]*c4.x + q[4*k+1]*c4.y + q[4*k+2]*c4.z + q[4*k+3]*c4.w;
      }
      d = 2.f*d - qs - cs[j];
      if (d > v[KK-1]) topk20_insert(d, m0 + j, v, id);
    }
  }
  __syncthreads();
#pragma unroll
  for (int k2=0;k2<KK;k2++){
    VL[(ql*16+sp)*KK + k2] = v[k2];
    IL[(ql*16+sp)*KK + k2] = id[k2];
  }
  __syncthreads();
  if (t < 16){
    float hv[16]; int hi_[16]; int hp[16];
#pragma unroll
    for (int s=0;s<16;s++){ hp[s]=0; hv[s]=VL[(t*16+s)*KK]; hi_[s]=IL[(t*16+s)*KK]; }
    int nq = n_base + t;
    for (int r=0;r<KK;r++){
      float bv = hv[0]; int bi = hi_[0]; int bs = 0;
#pragma unroll
      for (int s=1;s<16;s++){
        bool win = (hv[s] > bv) || ((hv[s] == bv) && (hi_[s] < bi));
        bv = win ? hv[s] : bv; bi = win ? hi_[s] : bi; bs = win ? s : bs;
      }
      IDX[((size_t)b*KK + r)*NN + nq] = bi;
#pragma unroll
      for (int s=0;s<16;s++){
        if (s == bs){
          int np = hp[s] + 1; hp[s] = np;
          bool ok = np < KK;
          hv[s]  = ok ? VL[(t*16+s)*KK + np] : -INFINITY;
          hi_[s] = ok ? IL[(t*16+s)*KK + np] : 0x7FFFFFFF;
        }
      }
    }
  }
}

// ---------- gather-max + BN + lrelu; idx loaded once per point, reused for 16 channels ----------
__global__ __launch_bounds__(256) void k_edge_apply(const float* __restrict__ Y, const float* __restrict__ T,
                             const int* __restrict__ IDX,
                             const float* __restrict__ g, const float* __restrict__ be,
                             const float* __restrict__ mu, const float* __restrict__ va,
                             float* __restrict__ OUT, int c_off){
  int t = threadIdx.x;
  int nl = t & 127, oh = t >> 7;
  int n = blockIdx.x*128 + nl;
  int b = blockIdx.z;
  int o0 = blockIdx.y*32 + oh*16;
  int idx[KK];
#pragma unroll
  for (int k2=0;k2<KK;k2++) idx[k2] = IDX[((size_t)b*KK + k2)*NN + n];
  for (int oo=0;oo<16;oo++){
    int o = o0 + oo;
    const float* yrow = Y + ((size_t)b*128 + o)*NN;
    float M = -INFINITY;
#pragma unroll
    for (int k2=0;k2<KK;k2++) M = fmaxf(M, yrow[idx[k2]]);
    float s = g[o] * rsqrtf(va[o] + EPSF);
    float val = s*(M + T[((size_t)b*128 + o)*NN + n] - mu[o]) + be[o];
    OUT[((size_t)b*256 + c_off + o)*NN + n] = lrelu(val);
  }
}

// ---------- y = Wa*X, t = (Wb-Wa)*X  (W is (O,128): [Wa | Wb]) ----------
template<int O>
__global__ __launch_bounds__(256) void k_yt_gemm(const float* __restrict__ X, const float* __restrict__ W,
                                                 float* __restrict__ Y, float* __restrict__ T){
  __shared__ __align__(16) float wa[O][64];
  __shared__ __align__(16) float wd[O][64];
  int t = threadIdx.x;
  for (int i=t; i<O*64; i+=256){
    int o = i >> 6, c = i & 63;
    float a = W[o*128 + c];
    wa[o][c] = a;
    wd[o][c] = W[o*128 + 64 + c] - a;
  }
  __syncthreads();
  int half = t >> 7, ln = t & 127;
  int gid = blockIdx.x*128 + ln;
  int b = gid >> 11, n = gid & (NN-1);
  const float* xb = X + (size_t)b*256*NN;
  float q[64];
#pragma unroll
  for (int c=0;c<64;c++) q[c] = xb[(size_t)c*NN + n];
  int o0 = half * (O/2);
  for (int o=o0; o<o0+O/2; ++o){
    float ay=0.f, at=0.f;
#pragma unroll
    for (int c=0;c<64;c+=4){
      float4 a4 = *(const float4*)&wa[o][c];
      float4 d4 = *(const float4*)&wd[o][c];
      ay += a4.x*q[c] + a4.y*q[c+1] + a4.z*q[c+2] + a4.w*q[c+3];
      at += d4.x*q[c] + d4.y*q[c+1] + d4.z*q[c+2] + d4.w*q[c+3];
    }
    Y[((size_t)b*128 + o)*NN + n] = ay;
    T[((size_t)b*128 + o)*NN + n] = at;
  }
}

// ---------- W4 GEMM with on-the-fly partial max over n ----------
__global__ __launch_bounds__(256) void k_w4max(const float* __restrict__ CAT, const float* __restrict__ W4,
                                               float* __restrict__ PART){
  __shared__ __align__(16) float wt[64][68];   // [c][o]
  __shared__ __align__(16) float ct[64][68];   // [c][n]
  int t = threadIdx.x;
  int io = t >> 4, in_ = t & 15;
  int nb = blockIdx.x * 64, ob = blockIdx.y * 64, b = blockIdx.z;
  const float* catb = CAT + (size_t)b*256*NN;
  float acc[4][4];
#pragma unroll
  for (int r=0;r<4;r++)
#pragma unroll
    for (int c=0;c<4;c++) acc[r][c]=0.f;
  for (int c0=0; c0<256; c0+=64){
    __syncthreads();
    for (int i=t; i<4096; i+=256){
      int oo = i >> 6, cc = i & 63;
      wt[cc][oo] = W4[(size_t)(ob+oo)*256 + c0 + cc];
    }
    for (int i=t; i<4096; i+=256){
      int cc = i >> 6, nn2 = i & 63;
      ct[cc][nn2] = catb[(size_t)(c0+cc)*NN + nb + nn2];
    }
    __syncthreads();
#pragma unroll 4
    for (int c=0;c<64;c++){
      float4 wv = *(const float4*)&wt[c][io*4];
      float4 cv = *(const float4*)&ct[c][in_*4];
      acc[0][0] += wv.x*cv.x; acc[0][1] += wv.x*cv.y; acc[0][2] += wv.x*cv.z; acc[0][3] += wv.x*cv.w;
      acc[1][0] += wv.y*cv.x; acc[1][1] += wv.y*cv.y; acc[1][2] += wv.y*cv.z; acc[1][3] += wv.y*cv.w;
      acc[2][0] += wv.z*cv.x; acc[2][1] += wv.z*cv.y; acc[2][2] += wv.z*cv.z; acc[2][3] += wv.z*cv.w;
      acc[3][0] += wv.w*cv.x; acc[3][1] += wv.w*cv.y; acc[3][2] += wv.w*cv.z; acc[3][3] += wv.w*cv.w;
    }
  }
#pragma unroll
  for (int r=0;r<4;r++){
    float m = fmaxf(fmaxf(acc[r][0], acc[r][1]), fmaxf(acc[r][2], acc[r][3]));
    m = fmaxf(m, __shfl_xor(m, 1));
    m = fmaxf(m, __shfl_xor(m, 2));
    m = fmaxf(m, __shfl_xor(m, 4));
    m = fmaxf(m, __shfl_xor(m, 8));
    if (in_ == 0){
      int o = ob + io*4 + r;
      PART[((size_t)b*1024 + o)*32 + blockIdx.x] = m;
    }
  }
}

__global__ void k_reduce4(const float* __restrict__ PART,
                          const float* __restrict__ g, const float* __restrict__ be,
                          const float* __restrict__ mu, const float* __restrict__ va,
                          float* __restrict__ H4){
  int gid = blockIdx.x*256 + threadIdx.x;   // B*1024
  int o = gid & 1023;
  float M = -INFINITY;
#pragma unroll
  for (int i=0;i<32;i++) M = fmaxf(M, PART[(size_t)gid*32 + i]);
  float s = g[o]*rsqrtf(va[o]+EPSF);
  H4[gid] = lrelu(s*(M - mu[o]) + be[o]);
}

__global__ __launch_bounds__(256) void k_mlp(const float* __restrict__ H4,
      const float* __restrict__ l1w, const float* __restrict__ l1b,
      const float* __restrict__ g5, const float* __restrict__ b5,
      const float* __restrict__ m5, const float* __restrict__ v5,
      const float* __restrict__ l2w, const float* __restrict__ l2b,
      const float* __restrict__ g6, const float* __restrict__ b6,
      const float* __restrict__ m6, const float* __restrict__ v6,
      const float* __restrict__ l3w, const float* __restrict__ l3b,
      float* __restrict__ out){
  __shared__ float h[1024];
  __shared__ float h5[512];
  __shared__ float h6[256];
  int b = blockIdx.x, t = threadIdx.x;
  for (int i=t;i<1024;i+=256) h[i] = H4[b*1024+i];
  __syncthreads();
  for (int o=t;o<512;o+=256){
    float acc = l1b[o];
    for (int c=0;c<1024;c+=4){
      float4 w = *(const float4*)&l1w[(size_t)o*1024 + c];
      acc += w.x*h[c] + w.y*h[c+1] + w.z*h[c+2] + w.w*h[c+3];
    }
    float s = g5[o]*rsqrtf(v5[o]+EPSF);
    h5[o] = lrelu(s*(acc - m5[o]) + b5[o]);
  }
  __syncthreads();
  if (t < 256){
    int o = t;
    float acc = l2b[o];
    for (int c=0;c<512;c+=4){
      float4 w = *(const float4*)&l2w[(size_t)o*512 + c];
      acc += w.x*h5[c] + w.y*h5[c+1] + w.z*h5[c+2] + w.w*h5[c+3];
    }
    float s = g6[o]*rsqrtf(v6[o]+EPSF);
    h6[o] = lrelu(s*(acc - m6[o]) + b6[o]);
  }
  __syncthreads();
  if (t < 128){
    int o = t >> 6, l = t & 63;
    float p = 0.f;
#pragma unroll
    for (int j=0;j<4;j++){ int c = j*64 + l; p += l3w[o*256 + c]*h6[c]; }
    p += __shfl_xor(p, 32); p += __shfl_xor(p, 16); p += __shfl_xor(p, 8);
    p += __shfl_xor(p, 4);  p += __shfl_xor(p, 2);  p += __shfl_xor(p, 1);
    if (l == 0) out[b*2 + o] = p + l3b[o];
  }
}

extern "C" void kernel_launch(void* const* d_in, const int* in_sizes, int n_in,
                              void* d_out, int out_size, void* d_ws, size_t ws_size,
                              hipStream_t stream){
  (void)in_sizes; (void)n_in; (void)out_size; (void)ws_size;
  const float* x    = (const float*)d_in[0];
  const float* W1   = (const float*)d_in[1];
  const float* bn1g = (const float*)d_in[2];
  const float* bn1b = (const float*)d_in[3];
  const float* bn1m = (const float*)d_in[4];
  const float* bn1v = (const float*)d_in[5];
  const float* W2   = (const float*)d_in[6];
  const float* bn2g = (const float*)d_in[7];
  const float* bn2b = (const float*)d_in[8];
  const float* bn2m = (const float*)d_in[9];
  const float* bn2v = (const float*)d_in[10];
  const float* W3   = (const float*)d_in[11];
  const float* bn3g = (const float*)d_in[12];
  const float* bn3b = (const float*)d_in[13];
  const float* bn3m = (const float*)d_in[14];
  const float* bn3v = (const float*)d_in[15];
  const float* W4   = (const float*)d_in[16];
  const float* bn4g = (const float*)d_in[17];
  const float* bn4b = (const float*)d_in[18];
  const float* bn4m = (const float*)d_in[19];
  const float* bn4v = (const float*)d_in[20];
  const float* l1w  = (const float*)d_in[21];
  const float* l1b  = (const float*)d_in[22];
  const float* bn5g = (const float*)d_in[23];
  const float* bn5b = (const float*)d_in[24];
  const float* bn5m = (const float*)d_in[25];
  const float* bn5v = (const float*)d_in[26];
  const float* l2w  = (const float*)d_in[27];
  const float* l2b  = (const float*)d_in[28];
  const float* bn6g = (const float*)d_in[29];
  const float* bn6b = (const float*)d_in[30];
  const float* bn6m = (const float*)d_in[31];
  const float* bn6v = (const float*)d_in[32];
  const float* l3w  = (const float*)d_in[33];
  const float* l3b  = (const float*)d_in[34];

  float* CAT  = (float*)d_ws;                          // [8][256][2048]
  float* Yb   = CAT + (size_t)8*256*NN;                // [8][128][2048]
  float* Tb   = Yb  + (size_t)8*128*NN;                // [8][128][2048]
  float* SQ   = Tb  + (size_t)8*128*NN;                // [8][2048]
  int*   IDX  = (int*)(SQ + (size_t)8*NN);             // [8][20][2048]
  float* PART = (float*)(IDX + (size_t)8*KK*NN);       // [8][1024][32]
  float* H4   = PART + (size_t)8*1024*32;              // [8][1024]

  // ---- block 1 ----
  k_prep1<<<64,256,0,stream>>>(x, W1, Yb, Tb, SQ);
  k_knn3<<<1024,256,0,stream>>>(x, SQ, IDX);
  k_edge_apply<<<dim3(16,2,8),256,0,stream>>>(Yb, Tb, IDX, bn1g, bn1b, bn1m, bn1v, CAT, 0);
  // ---- block 2 (features = CAT ch 0..63) ----
  k_sqnorm<<<64,256,0,stream>>>(CAT, SQ);
  k_knn64<<<1024,256,0,stream>>>(CAT, SQ, IDX);
  k_yt_gemm<64><<<128,256,0,stream>>>(CAT, W2, Yb, Tb);
  k_edge_apply<<<dim3(16,2,8),256,0,stream>>>(Yb, Tb, IDX, bn2g, bn2b, bn2m, bn2v, CAT, 64);
  // ---- block 3 (features = CAT ch 64..127) ----
  k_sqnorm<<<64,256,0,stream>>>(CAT + (size_t)64*NN, SQ);
  k_knn64<<<1024,256,0,stream>>>(CAT + (size_t)64*NN, SQ, IDX);
  k_yt_gemm<128><<<128,256,0,stream>>>(CAT + (size_t)64*NN, W3, Yb, Tb);
  k_edge_apply<<<dim3(16,4,8),256,0,stream>>>(Yb, Tb, IDX, bn3g, bn3b, bn3m, bn3v, CAT, 128);
  // ---- W4 + global max pool ----
  k_w4max<<<dim3(32,16,8),256,0,stream>>>(CAT, W4, PART);
  k_reduce4<<<32,256,0,stream>>>(PART, bn4g, bn4b, bn4m, bn4v, H4);
  // ---- MLP head ----
  k_mlp<<<8,256,0,stream>>>(H4, l1w, l1b, bn5g, bn5b, bn5m, bn5v,
                            l2w, l2b, bn6g, bn6b, bn6m, bn6v, l3w, l3b, (float*)d_out);
}

// Round 5
// 1501.252 us; speedup vs baseline: 1.3145x; 1.0538x over previous
//
#include <hip/hip_runtime.h>
#include <math.h>

#define NN 2048
#define KK 20
#define EPSF 1e-5f

__device__ __forceinline__ float lrelu(float v){ return v >= 0.f ? v : 0.2f*v; }

// Sorted (descending, ties by ascending id) top-20 insert. Caller guards d > v[19].
__device__ __forceinline__ void topk20_insert(float d, int idc, float (&v)[KK], int (&id)[KK]){
#pragma unroll
  for (int j = KK-1; j >= 1; --j){
    bool cjm1 = d > v[j-1];
    bool cj   = d > v[j];
    float nv = cjm1 ? v[j-1] : (cj ? d   : v[j]);
    int   ni = cjm1 ? id[j-1] : (cj ? idc : id[j]);
    v[j] = nv; id[j] = ni;
  }
  if (d > v[0]) { v[0] = d; id[0] = idc; }
}

// ---------- stage 1 prep: sq norms + y1 = Wa1*x, t1 = (Wb1-Wa1)*x ----------
__global__ void k_prep1(const float* __restrict__ x, const float* __restrict__ W1,
                        float* __restrict__ Y, float* __restrict__ T, float* __restrict__ SQ){
  __shared__ float wa[64][3], wd[64][3];
  int t = threadIdx.x;
  if (t < 64){
#pragma unroll
    for (int c=0;c<3;c++){
      float a = W1[t*6+c], b2 = W1[t*6+3+c];
      wa[t][c] = a; wd[t][c] = b2 - a;
    }
  }
  __syncthreads();
  int gid = blockIdx.x*256 + t;
  int b = gid >> 11, n = gid & (NN-1);
  float px = x[gid*3+0], py = x[gid*3+1], pz = x[gid*3+2];
  SQ[gid] = px*px + py*py + pz*pz;
  float* yb = Y + ((size_t)b*128)*NN + n;
  float* tb = T + ((size_t)b*128)*NN + n;
#pragma unroll 8
  for (int o=0;o<64;o++){
    yb[(size_t)o*NN] = wa[o][0]*px + wa[o][1]*py + wa[o][2]*pz;
    tb[(size_t)o*NN] = wd[o][0]*px + wd[o][1]*py + wd[o][2]*pz;
  }
}

// ---------- KNN on raw xyz (C=3), QB=32 queries x NSP=8 splits ----------
// LDS: phase1 cd[128][4] (2048 B); phase2 VL f32[256][20] (20480) + IL u16[256][20] (10240) = 30720 B.
__global__ __launch_bounds__(256) void k_knn3(const float* __restrict__ x, const float* __restrict__ SQ,
                                              int* __restrict__ IDX){
  __shared__ __align__(16) unsigned char smem[30720];
  float* cd = (float*)smem;            // [128][4] xyz+sq  (phase 1)
  float* VL = (float*)smem;            // [256][20]        (phase 2)
  unsigned short* IL = (unsigned short*)(smem + 20480);
  int t = threadIdx.x;
  int b = blockIdx.x >> 6;
  int n_base = (blockIdx.x & 63) * 32;
  int ql = t & 31, sp = t >> 5;
  int n = n_base + ql;
  int gq = b*NN + n;
  float qx = x[gq*3], qy = x[gq*3+1], qz = x[gq*3+2];
  float qs = SQ[gq];
  float v[KK]; int id[KK];
#pragma unroll
  for (int i=0;i<KK;i++){ v[i] = -INFINITY; id[i] = 0; }
  int mlo = sp * 16;
  for (int tile=0; tile<16; ++tile){
    int m0 = tile * 128;
    __syncthreads();
#pragma unroll
    for (int i=0;i<2;i++){
      int f2 = t + i*256;
      int m = f2 >> 2, ch = f2 & 3;
      int gm = b*NN + m0 + m;
      cd[f2] = (ch < 3) ? x[gm*3 + ch] : SQ[gm];
    }
    __syncthreads();
    for (int j=mlo; j<mlo+16; ++j){
      float4 c4 = *(const float4*)&cd[j*4];
      float d = 2.f*(qx*c4.x + qy*c4.y + qz*c4.z) - qs - c4.w;
      if (d > v[KK-1]) topk20_insert(d, m0 + j, v, id);
    }
  }
  __syncthreads();
#pragma unroll
  for (int k2=0;k2<KK;k2++){
    VL[(ql*8+sp)*KK + k2] = v[k2];
    IL[(ql*8+sp)*KK + k2] = (unsigned short)id[k2];
  }
  __syncthreads();
  if (t < 32){
    float hv[8]; int hi_[8]; int hp[8];
#pragma unroll
    for (int s=0;s<8;s++){ hp[s]=0; hv[s]=VL[(t*8+s)*KK]; hi_[s]=(int)IL[(t*8+s)*KK]; }
    int nq = n_base + t;
    for (int r=0;r<KK;r++){
      float bv = hv[0]; int bi = hi_[0]; int bs = 0;
#pragma unroll
      for (int s=1;s<8;s++){
        bool win = (hv[s] > bv) || ((hv[s] == bv) && (hi_[s] < bi));
        bv = win ? hv[s] : bv; bi = win ? hi_[s] : bi; bs = win ? s : bs;
      }
      IDX[((size_t)b*KK + r)*NN + nq] = bi;
#pragma unroll
      for (int s=0;s<8;s++){
        if (s == bs){
          int np = hp[s] + 1; hp[s] = np;
          bool ok = np < KK;
          hv[s]  = ok ? VL[(t*8+s)*KK + np] : -INFINITY;
          hi_[s] = ok ? (int)IL[(t*8+s)*KK + np] : 0x7FFFFFFF;
        }
      }
    }
  }
}

// ---------- squared norms of a 64-channel feature region ----------
__global__ void k_sqnorm(const float* __restrict__ X, float* __restrict__ SQ){
  int gid = blockIdx.x*256 + threadIdx.x;
  int b = gid >> 11, n = gid & (NN-1);
  const float* xb = X + (size_t)b*256*NN;
  float s = 0.f;
#pragma unroll
  for (int c=0;c<64;c++){ float vv = xb[(size_t)c*NN + n]; s += vv*vv; }
  SQ[gid] = s;
}

// ---------- KNN on 64-channel features, QB=32 x NSP=8 ----------
// LDS: phase1 cd[128][68] (34816) + cs[128] (512) = 35328 B; phase2 VL+IL(u16) = 30720 B (aliased).
__global__ __launch_bounds__(256) void k_knn64(const float* __restrict__ X, const float* __restrict__ SQ,
                                               int* __restrict__ IDX){
  __shared__ __align__(16) unsigned char smem[35328];
  float* cd = (float*)smem;                 // [128][68]  (phase 1)
  float* cs = (float*)(smem + 34816);       // [128]
  float* VL = (float*)smem;                 // [256][20]  (phase 2)
  unsigned short* IL = (unsigned short*)(smem + 20480);
  int t = threadIdx.x;
  int b = blockIdx.x >> 6;
  int n_base = (blockIdx.x & 63) * 32;
  int ql = t & 31, sp = t >> 5;
  int n = n_base + ql;
  const float* xb = X + (size_t)b*256*NN;
  float q[64];
#pragma unroll
  for (int c=0;c<64;c++) q[c] = xb[(size_t)c*NN + n];
  float qs = SQ[b*NN + n];
  float v[KK]; int id[KK];
#pragma unroll
  for (int i=0;i<KK;i++){ v[i]=-INFINITY; id[i]=0; }
  int mlo = sp * 16;
  for (int tile=0; tile<16; ++tile){
    int m0 = tile*128;
    __syncthreads();
#pragma unroll
    for (int i=0;i<32;i++){
      int flat = i*256 + t;
      int c = flat >> 7, m = flat & 127;
      cd[m*68 + c] = xb[(size_t)c*NN + m0 + m];
    }
    if (t < 128) cs[t] = SQ[b*NN + m0 + t];
    __syncthreads();
    for (int j=mlo; j<mlo+16; ++j){
      const float* crow = cd + j*68;
      float d = 0.f;
#pragma unroll
      for (int c=0;c<64;c+=4){
        float4 c4 = *(const float4*)&crow[c];
        d += q[c]*c4.x + q[c+1]*c4.y + q[c+2]*c4.z + q[c+3]*c4.w;
      }
      d = 2.f*d - qs - cs[j];
      if (d > v[KK-1]) topk20_insert(d, m0 + j, v, id);
    }
  }
  __syncthreads();
#pragma unroll
  for (int k2=0;k2<KK;k2++){
    VL[(ql*8+sp)*KK + k2] = v[k2];
    IL[(ql*8+sp)*KK + k2] = (unsigned short)id[k2];
  }
  __syncthreads();
  if (t < 32){
    float hv[8]; int hi_[8]; int hp[8];
#pragma unroll
    for (int s=0;s<8;s++){ hp[s]=0; hv[s]=VL[(t*8+s)*KK]; hi_[s]=(int)IL[(t*8+s)*KK]; }
    int nq = n_base + t;
    for (int r=0;r<KK;r++){
      float bv = hv[0]; int bi = hi_[0]; int bs = 0;
#pragma unroll
      for (int s=1;s<8;s++){
        bool win = (hv[s] > bv) || ((hv[s] == bv) && (hi_[s] < bi));
        bv = win ? hv[s] : bv; bi = win ? hi_[s] : bi; bs = win ? s : bs;
      }
      IDX[((size_t)b*KK + r)*NN + nq] = bi;
#pragma unroll
      for (int s=0;s<8;s++){
        if (s == bs){
          int np = hp[s] + 1; hp[s] = np;
          bool ok = np < KK;
          hv[s]  = ok ? VL[(t*8+s)*KK + np] : -INFINITY;
          hi_[s] = ok ? (int)IL[(t*8+s)*KK + np] : 0x7FFFFFFF;
        }
      }
    }
  }
}

// ---------- gather-max + BN + lrelu; idx loaded once per point, reused for 16 channels ----------
__global__ __launch_bounds__(256) void k_edge_apply(const float* __restrict__ Y, const float* __restrict__ T,
                             const int* __restrict__ IDX,
                             const float* __restrict__ g, const float* __restrict__ be,
                             const float* __restrict__ mu, const float* __restrict__ va,
                             float* __restrict__ OUT, int c_off){
  int t = threadIdx.x;
  int nl = t & 127, oh = t >> 7;
  int n = blockIdx.x*128 + nl;
  int b = blockIdx.z;
  int o0 = blockIdx.y*32 + oh*16;
  int idx[KK];
#pragma unroll
  for (int k2=0;k2<KK;k2++) idx[k2] = IDX[((size_t)b*KK + k2)*NN + n];
  for (int oo=0;oo<16;oo++){
    int o = o0 + oo;
    const float* yrow = Y + ((size_t)b*128 + o)*NN;
    float M = -INFINITY;
#pragma unroll
    for (int k2=0;k2<KK;k2++) M = fmaxf(M, yrow[idx[k2]]);
    float s = g[o] * rsqrtf(va[o] + EPSF);
    float val = s*(M + T[((size_t)b*128 + o)*NN + n] - mu[o]) + be[o];
    OUT[((size_t)b*256 + c_off + o)*NN + n] = lrelu(val);
  }
}

// ---------- y = Wa*X, t = (Wb-Wa)*X  (W is (O,128): [Wa | Wb]) ----------
template<int O>
__global__ __launch_bounds__(256) void k_yt_gemm(const float* __restrict__ X, const float* __restrict__ W,
                                                 float* __restrict__ Y, float* __restrict__ T){
  __shared__ __align__(16) float wa[O][64];
  __shared__ __align__(16) float wd[O][64];
  int t = threadIdx.x;
  for (int i=t; i<O*64; i+=256){
    int o = i >> 6, c = i & 63;
    float a = W[o*128 + c];
    wa[o][c] = a;
    wd[o][c] = W[o*128 + 64 + c] - a;
  }
  __syncthreads();
  int half = t >> 7, ln = t & 127;
  int gid = blockIdx.x*128 + ln;
  int b = gid >> 11, n = gid & (NN-1);
  const float* xb = X + (size_t)b*256*NN;
  float q[64];
#pragma unroll
  for (int c=0;c<64;c++) q[c] = xb[(size_t)c*NN + n];
  int o0 = half * (O/2);
  for (int o=o0; o<o0+O/2; ++o){
    float ay=0.f, at=0.f;
#pragma unroll
    for (int c=0;c<64;c+=4){
      float4 a4 = *(const float4*)&wa[o][c];
      float4 d4 = *(const float4*)&wd[o][c];
      ay += a4.x*q[c] + a4.y*q[c+1] + a4.z*q[c+2] + a4.w*q[c+3];
      at += d4.x*q[c] + d4.y*q[c+1] + d4.z*q[c+2] + d4.w*q[c+3];
    }
    Y[((size_t)b*128 + o)*NN + n] = ay;
    T[((size_t)b*128 + o)*NN + n] = at;
  }
}

// ---------- W4 GEMM with on-the-fly partial max over n ----------
__global__ __launch_bounds__(256) void k_w4max(const float* __restrict__ CAT, const float* __restrict__ W4,
                                               float* __restrict__ PART){
  __shared__ __align__(16) float wt[64][68];   // [c][o]
  __shared__ __align__(16) float ct[64][68];   // [c][n]
  int t = threadIdx.x;
  int io = t >> 4, in_ = t & 15;
  int nb = blockIdx.x * 64, ob = blockIdx.y * 64, b = blockIdx.z;
  const float* catb = CAT + (size_t)b*256*NN;
  float acc[4][4];
#pragma unroll
  for (int r=0;r<4;r++)
#pragma unroll
    for (int c=0;c<4;c++) acc[r][c]=0.f;
  for (int c0=0; c0<256; c0+=64){
    __syncthreads();
    for (int i=t; i<4096; i+=256){
      int oo = i >> 6, cc = i & 63;
      wt[cc][oo] = W4[(size_t)(ob+oo)*256 + c0 + cc];
    }
    for (int i=t; i<4096; i+=256){
      int cc = i >> 6, nn2 = i & 63;
      ct[cc][nn2] = catb[(size_t)(c0+cc)*NN + nb + nn2];
    }
    __syncthreads();
#pragma unroll 4
    for (int c=0;c<64;c++){
      float4 wv = *(const float4*)&wt[c][io*4];
      float4 cv = *(const float4*)&ct[c][in_*4];
      acc[0][0] += wv.x*cv.x; acc[0][1] += wv.x*cv.y; acc[0][2] += wv.x*cv.z; acc[0][3] += wv.x*cv.w;
      acc[1][0] += wv.y*cv.x; acc[1][1] += wv.y*cv.y; acc[1][2] += wv.y*cv.z; acc[1][3] += wv.y*cv.w;
      acc[2][0] += wv.z*cv.x; acc[2][1] += wv.z*cv.y; acc[2][2] += wv.z*cv.z; acc[2][3] += wv.z*cv.w;
      acc[3][0] += wv.w*cv.x; acc[3][1] += wv.w*cv.y; acc[3][2] += wv.w*cv.z; acc[3][3] += wv.w*cv.w;
    }
  }
#pragma unroll
  for (int r=0;r<4;r++){
    float m = fmaxf(fmaxf(acc[r][0], acc[r][1]), fmaxf(acc[r][2], acc[r][3]));
    m = fmaxf(m, __shfl_xor(m, 1));
    m = fmaxf(m, __shfl_xor(m, 2));
    m = fmaxf(m, __shfl_xor(m, 4));
    m = fmaxf(m, __shfl_xor(m, 8));
    if (in_ == 0){
      int o = ob + io*4 + r;
      PART[((size_t)b*1024 + o)*32 + blockIdx.x] = m;
    }
  }
}

__global__ void k_reduce4(const float* __restrict__ PART,
                          const float* __restrict__ g, const float* __restrict__ be,
                          const float* __restrict__ mu, const float* __restrict__ va,
                          float* __restrict__ H4){
  int gid = blockIdx.x*256 + threadIdx.x;   // B*1024
  int o = gid & 1023;
  float M = -INFINITY;
#pragma unroll
  for (int i=0;i<32;i++) M = fmaxf(M, PART[(size_t)gid*32 + i]);
  float s = g[o]*rsqrtf(va[o]+EPSF);
  H4[gid] = lrelu(s*(M - mu[o]) + be[o]);
}

__global__ __launch_bounds__(256) void k_mlp(const float* __restrict__ H4,
      const float* __restrict__ l1w, const float* __restrict__ l1b,
      const float* __restrict__ g5, const float* __restrict__ b5,
      const float* __restrict__ m5, const float* __restrict__ v5,
      const float* __restrict__ l2w, const float* __restrict__ l2b,
      const float* __restrict__ g6, const float* __restrict__ b6,
      const float* __restrict__ m6, const float* __restrict__ v6,
      const float* __restrict__ l3w, const float* __restrict__ l3b,
      float* __restrict__ out){
  __shared__ float h[1024];
  __shared__ float h5[512];
  __shared__ float h6[256];
  int b = blockIdx.x, t = threadIdx.x;
  for (int i=t;i<1024;i+=256) h[i] = H4[b*1024+i];
  __syncthreads();
  for (int o=t;o<512;o+=256){
    float acc = l1b[o];
    for (int c=0;c<1024;c+=4){
      float4 w = *(const float4*)&l1w[(size_t)o*1024 + c];
      acc += w.x*h[c] + w.y*h[c+1] + w.z*h[c+2] + w.w*h[c+3];
    }
    float s = g5[o]*rsqrtf(v5[o]+EPSF);
    h5[o] = lrelu(s*(acc - m5[o]) + b5[o]);
  }
  __syncthreads();
  if (t < 256){
    int o = t;
    float acc = l2b[o];
    for (int c=0;c<512;c+=4){
      float4 w = *(const float4*)&l2w[(size_t)o*512 + c];
      acc += w.x*h5[c] + w.y*h5[c+1] + w.z*h5[c+2] + w.w*h5[c+3];
    }
    float s = g6[o]*rsqrtf(v6[o]+EPSF);
    h6[o] = lrelu(s*(acc - m6[o]) + b6[o]);
  }
  __syncthreads();
  if (t < 128){
    int o = t >> 6, l = t & 63;
    float p = 0.f;
#pragma unroll
    for (int j=0;j<4;j++){ int c = j*64 + l; p += l3w[o*256 + c]*h6[c]; }
    p += __shfl_xor(p, 32); p += __shfl_xor(p, 16); p += __shfl_xor(p, 8);
    p += __shfl_xor(p, 4);  p += __shfl_xor(p, 2);  p += __shfl_xor(p, 1);
    if (l == 0) out[b*2 + o] = p + l3b[o];
  }
}

extern "C" void kernel_launch(void* const* d_in, const int* in_sizes, int n_in,
                              void* d_out, int out_size, void* d_ws, size_t ws_size,
                              hipStream_t stream){
  (void)in_sizes; (void)n_in; (void)out_size; (void)ws_size;
  const float* x    = (const float*)d_in[0];
  const float* W1   = (const float*)d_in[1];
  const float* bn1g = (const float*)d_in[2];
  const float* bn1b = (const float*)d_in[3];
  const float* bn1m = (const float*)d_in[4];
  const float* bn1v = (const float*)d_in[5];
  const float* W2   = (const float*)d_in[6];
  const float* bn2g = (const float*)d_in[7];
  const float* bn2b = (const float*)d_in[8];
  const float* bn2m = (const float*)d_in[9];
  const float* bn2v = (const float*)d_in[10];
  const float* W3   = (const float*)d_in[11];
  const float* bn3g = (const float*)d_in[12];
  const float* bn3b = (const float*)d_in[13];
  const float* bn3m = (const float*)d_in[14];
  const float* bn3v = (const float*)d_in[15];
  const float* W4   = (const float*)d_in[16];
  const float* bn4g = (const float*)d_in[17];
  const float* bn4b = (const float*)d_in[18];
  const float* bn4m = (const float*)d_in[19];
  const float* bn4v = (const float*)d_in[20];
  const float* l1w  = (const float*)d_in[21];
  const float* l1b  = (const float*)d_in[22];
  const float* bn5g = (const float*)d_in[23];
  const float* bn5b = (const float*)d_in[24];
  const float* bn5m = (const float*)d_in[25];
  const float* bn5v = (const float*)d_in[26];
  const float* l2w  = (const float*)d_in[27];
  const float* l2b  = (const float*)d_in[28];
  const float* bn6g = (const float*)d_in[29];
  const float* bn6b = (const float*)d_in[30];
  const float* bn6m = (const float*)d_in[31];
  const float* bn6v = (const float*)d_in[32];
  const float* l3w  = (const float*)d_in[33];
  const float* l3b  = (const float*)d_in[34];

  float* CAT  = (float*)d_ws;                          // [8][256][2048]
  float* Yb   = CAT + (size_t)8*256*NN;                // [8][128][2048]
  float* Tb   = Yb  + (size_t)8*128*NN;                // [8][128][2048]
  float* SQ   = Tb  + (size_t)8*128*NN;                // [8][2048]
  int*   IDX  = (int*)(SQ + (size_t)8*NN);             // [8][20][2048]
  float* PART = (float*)(IDX + (size_t)8*KK*NN);       // [8][1024][32]
  float* H4   = PART + (size_t)8*1024*32;              // [8][1024]

  // ---- block 1 ----
  k_prep1<<<64,256,0,stream>>>(x, W1, Yb, Tb, SQ);
  k_knn3<<<512,256,0,stream>>>(x, SQ, IDX);
  k_edge_apply<<<dim3(16,2,8),256,0,stream>>>(Yb, Tb, IDX, bn1g, bn1b, bn1m, bn1v, CAT, 0);
  // ---- block 2 (features = CAT ch 0..63) ----
  k_sqnorm<<<64,256,0,stream>>>(CAT, SQ);
  k_knn64<<<512,256,0,stream>>>(CAT, SQ, IDX);
  k_yt_gemm<64><<<128,256,0,stream>>>(CAT, W2, Yb, Tb);
  k_edge_apply<<<dim3(16,2,8),256,0,stream>>>(Yb, Tb, IDX, bn2g, bn2b, bn2m, bn2v, CAT, 64);
  // ---- block 3 (features = CAT ch 64..127) ----
  k_sqnorm<<<64,256,0,stream>>>(CAT + (size_t)64*NN, SQ);
  k_knn64<<<512,256,0,stream>>>(CAT + (size_t)64*NN, SQ, IDX);
  k_yt_gemm<128><<<128,256,0,stream>>>(CAT + (size_t)64*NN, W3, Yb, Tb);
  k_edge_apply<<<dim3(16,4,8),256,0,stream>>>(Yb, Tb, IDX, bn3g, bn3b, bn3m, bn3v, CAT, 128);
  // ---- W4 + global max pool ----
  k_w4max<<<dim3(32,16,8),256,0,stream>>>(CAT, W4, PART);
  k_reduce4<<<32,256,0,stream>>>(PART, bn4g, bn4b, bn4m, bn4v, H4);
  // ---- MLP head ----
  k_mlp<<<8,256,0,stream>>>(H4, l1w, l1b, bn5g, bn5b, bn5m, bn5v,
                            l2w, l2b, bn6g, bn6b, bn6m, bn6v, l3w, l3b, (float*)d_out);
}